// Round 2
// baseline (465.547 us; speedup 1.0000x reference)
//
#include <hip/hip_runtime.h>
#include <stdint.h>

#define NROWS 8192
#define KDIM  8192
#define DIN   256
#define DOUT  256

typedef __attribute__((ext_vector_type(8))) short bf16x8;   // 8 bf16 in 4 VGPRs
typedef __attribute__((ext_vector_type(4))) float f32x4;

__device__ __forceinline__ unsigned short f2bf(float f) {
    union { float f; unsigned u; } v; v.f = f;
    unsigned r = v.u + 0x7FFFu + ((v.u >> 16) & 1u);   // RNE
    return (unsigned short)(r >> 16);
}

__device__ __forceinline__ void async_load16(const void* g, void* l) {
    __builtin_amdgcn_global_load_lds(
        (__attribute__((address_space(1))) void*)(void*)g,
        (__attribute__((address_space(3))) void*)l, 16, 0, 0);
}

// ---------------- kernel 1: dis[i] = rsqrt(rowsum(A)); Abf = bf16(A) ----------------
// 384 MB streaming (256 r + 128 w) -> ~61 us.
__global__ __launch_bounds__(256) void k_rowsum_cvt(const float* __restrict__ A,
                                                    float* __restrict__ dis,
                                                    unsigned short* __restrict__ Abf) {
    const int wave = threadIdx.x >> 6, lane = threadIdx.x & 63;
    const int row = (blockIdx.x << 2) + wave;
    const float4* rp = (const float4*)(A + (size_t)row * KDIM);
    short4* wp = (short4*)(Abf + (size_t)row * KDIM);
    float s0 = 0.f, s1 = 0.f;
    #pragma unroll
    for (int it = 0; it < 32; it += 2) {
        float4 v0 = rp[(it + 0) * 64 + lane];
        float4 v1 = rp[(it + 1) * 64 + lane];
        short4 b0, b1;
        b0.x = (short)f2bf(v0.x); b0.y = (short)f2bf(v0.y);
        b0.z = (short)f2bf(v0.z); b0.w = (short)f2bf(v0.w);
        b1.x = (short)f2bf(v1.x); b1.y = (short)f2bf(v1.y);
        b1.z = (short)f2bf(v1.z); b1.w = (short)f2bf(v1.w);
        wp[(it + 0) * 64 + lane] = b0;
        wp[(it + 1) * 64 + lane] = b1;
        s0 += (v0.x + v0.y) + (v0.z + v0.w);
        s1 += (v1.x + v1.y) + (v1.z + v1.w);
    }
    float s = s0 + s1;
    #pragma unroll
    for (int off = 32; off > 0; off >>= 1) s += __shfl_down(s, off, 64);
    if (lane == 0) dis[row] = rsqrtf(s);
}

// ---------------- kernel 2: Zst[n][j] = dis[j] * (X @ W^T)[j][n]  (bf16, transposed) ----------------
__global__ __launch_bounds__(256, 2) void k_xw(const float* __restrict__ X,
                                               const float* __restrict__ W,
                                               const float* __restrict__ dis,
                                               unsigned short* __restrict__ Zst) {
    __shared__ short sX[64 * 72];
    __shared__ short sW[256 * 72];
    __shared__ float disS[64];
    const int tid = threadIdx.x;
    const int w = tid >> 6, lane = tid & 63, lm = lane & 15, lq = lane >> 4;
    const int j0 = blockIdx.x * 64;
    if (tid < 64) disS[tid] = dis[j0 + tid];
    f32x4 acc[4][4] = {};

    for (int s = 0; s < 4; ++s) {
        const int k0 = s * 64;
        #pragma unroll
        for (int i = 0; i < 4; ++i) {
            int e = tid + i * 256;
            int row = e >> 4, c4 = e & 15;
            float4 v = *(const float4*)(X + (size_t)(j0 + row) * DIN + k0 + c4 * 4);
            short4 b; b.x = (short)f2bf(v.x); b.y = (short)f2bf(v.y);
            b.z = (short)f2bf(v.z); b.w = (short)f2bf(v.w);
            *(short4*)&sX[row * 72 + c4 * 4] = b;
        }
        #pragma unroll
        for (int i = 0; i < 16; ++i) {
            int e = tid + i * 256;
            int row = e >> 4, c4 = e & 15;
            float4 v = *(const float4*)(W + (size_t)row * DIN + k0 + c4 * 4);
            short4 b; b.x = (short)f2bf(v.x); b.y = (short)f2bf(v.y);
            b.z = (short)f2bf(v.z); b.w = (short)f2bf(v.w);
            *(short4*)&sW[row * 72 + c4 * 4] = b;
        }
        __syncthreads();
        #pragma unroll
        for (int kk = 0; kk < 2; ++kk) {
            const int koff = kk * 32 + lq * 8;
            bf16x8 a[4], b[4];
            #pragma unroll
            for (int mt = 0; mt < 4; ++mt)
                a[mt] = *(const bf16x8*)&sX[(mt * 16 + lm) * 72 + koff];
            #pragma unroll
            for (int nt = 0; nt < 4; ++nt)
                b[nt] = *(const bf16x8*)&sW[(w * 64 + nt * 16 + lm) * 72 + koff];
            #pragma unroll
            for (int mt = 0; mt < 4; ++mt)
                #pragma unroll
                for (int nt = 0; nt < 4; ++nt)
                    acc[mt][nt] = __builtin_amdgcn_mfma_f32_16x16x32_bf16(
                        a[mt], b[nt], acc[mt][nt], 0, 0, 0);
        }
        __syncthreads();
    }

    #pragma unroll
    for (int mt = 0; mt < 4; ++mt)
        #pragma unroll
        for (int nt = 0; nt < 4; ++nt)
            #pragma unroll
            for (int r = 0; r < 4; ++r) {
                int jl = mt * 16 + lq * 4 + r;
                int n  = w * 64 + nt * 16 + lm;
                float v = acc[mt][nt][r] * disS[jl];
                sW[n * 72 + jl] = (short)f2bf(v);
            }
    __syncthreads();
    #pragma unroll
    for (int it = 0; it < 8; ++it) {
        int e = tid + it * 256;
        int n = e >> 3, ch = e & 7;
        bf16x8 val = *(const bf16x8*)&sW[n * 72 + ch * 8];
        *(bf16x8*)(Zst + (size_t)n * NROWS + j0 + ch * 8) = val;
    }
}

// ---------------- kernel 3 (fast path): pure-async bf16 GEMM ----------------
// out_part[split][i][o] = sum_{j in split} Abf[i][j] * Zst[o][j], scaled by dis[i].
// BM=64, BN=256, BK=64, SPLITK=4 -> 512 blocks, 2/CU. K-loop: 10 global_load_lds
// issues + 32 MFMA per wave per step, no staging VALU.
__global__ __launch_bounds__(256, 2) void k_gemm_bf(const unsigned short* __restrict__ Abf,
                                                    const unsigned short* __restrict__ Zst,
                                                    const float* __restrict__ dis,
                                                    float* __restrict__ part) {
    __shared__ short sA[64 * 64];     // packed, XOR-swizzled 16B chunks
    __shared__ short sB[256 * 64];    // 4 wave-slabs, packed, XOR-swizzled
    __shared__ float disS[64];
    const int tid = threadIdx.x;
    const int w = tid >> 6, lane = tid & 63, lm = lane & 15, lq = lane >> 4;
    const int m0 = blockIdx.x * 64;
    const int split = blockIdx.y;
    const int kbase = split * 2048;
    if (tid < 64) disS[tid] = dis[m0 + tid];
    f32x4 acc[4][4] = {};
    short* sAw = &sA[w * 1024];       // wave w stages A rows w*16 .. w*16+15
    short* sBw = &sB[w * 4096];       // wave w stages B rows w*64 .. w*64+63
    // chunk swizzle: LDS slot sc of row r holds k-chunk c = sc ^ (r & 7)
    const int swz = (lane & 7) ^ (lane >> 3);
    const unsigned short* gA =
        Abf + (size_t)(m0 + w * 16 + (lane >> 3)) * KDIM + kbase + swz * 8;
    const unsigned short* gB =
        Zst + (size_t)(w * 64 + (lane >> 3)) * KDIM + kbase + swz * 8;

    for (int s = 0; s < 32; ++s) {
        const int kofs = s * 64;
        #pragma unroll
        for (int i = 0; i < 2; ++i)
            async_load16(gA + kofs + (size_t)i * 8 * KDIM, &sAw[i * 512]);
        #pragma unroll
        for (int i = 0; i < 8; ++i)
            async_load16(gB + kofs + (size_t)i * 8 * KDIM, &sBw[i * 512]);
        __syncthreads();
        #pragma unroll
        for (int kk = 0; kk < 2; ++kk) {
            const int cb = kk * 4 + lq;               // k-chunk 0..7
            const int scb = cb ^ (lm & 7);            // undo swizzle (row&7 == lm&7)
            bf16x8 a[4], b[4];
            #pragma unroll
            for (int mt = 0; mt < 4; ++mt)
                a[mt] = *(const bf16x8*)&sA[(mt * 16 + lm) * 64 + scb * 8];
            #pragma unroll
            for (int nt = 0; nt < 4; ++nt)
                b[nt] = *(const bf16x8*)&sBw[(nt * 16 + lm) * 64 + scb * 8];
            #pragma unroll
            for (int mt = 0; mt < 4; ++mt)
                #pragma unroll
                for (int nt = 0; nt < 4; ++nt)
                    acc[mt][nt] = __builtin_amdgcn_mfma_f32_16x16x32_bf16(
                        a[mt], b[nt], acc[mt][nt], 0, 0, 0);
        }
        __syncthreads();
    }

    #pragma unroll
    for (int mt = 0; mt < 4; ++mt)
        #pragma unroll
        for (int nt = 0; nt < 4; ++nt) {
            int col = w * 64 + nt * 16 + lm;
            #pragma unroll
            for (int r = 0; r < 4; ++r) {
                int rl = mt * 16 + lq * 4 + r;
                float v = acc[mt][nt][r] * disS[rl];
                part[(size_t)split * (NROWS * DOUT) + (size_t)(m0 + rl) * DOUT + col] = v;
            }
        }
}

// ---------------- kernel 3 (fallback, small ws): fp32-A staging, atomic out ----------------
__global__ __launch_bounds__(256, 2) void k_gemm_f32(const float* __restrict__ A,
                                                     const unsigned short* __restrict__ Zst,
                                                     const float* __restrict__ dis,
                                                     float* __restrict__ out) {
    __shared__ short sA[64 * 72];
    __shared__ short sB[256 * 64];
    __shared__ float disS[64];
    const int tid = threadIdx.x;
    const int w = tid >> 6, lane = tid & 63, lm = lane & 15, lq = lane >> 4;
    const int m0 = blockIdx.x * 64;
    const int split = blockIdx.y;
    const int kbase = split * 2048;
    if (tid < 64) disS[tid] = dis[m0 + tid];
    f32x4 acc[4][4] = {};
    short* sBw = &sB[w * 4096];
    const int arow = tid >> 4, ac4 = tid & 15;
    const int swz = (lane & 7) ^ (lane >> 3);

    for (int s = 0; s < 32; ++s) {
        const int k0 = kbase + s * 64;
        const unsigned short* gB =
            Zst + (size_t)(w * 64 + (lane >> 3)) * KDIM + k0 + swz * 8;
        #pragma unroll
        for (int i = 0; i < 8; ++i)
            async_load16(gB + (size_t)i * 8 * KDIM, &sBw[i * 512]);
        #pragma unroll
        for (int i = 0; i < 4; ++i) {
            int row = arow + i * 16;
            float4 v = *(const float4*)(A + (size_t)(m0 + row) * KDIM + k0 + ac4 * 4);
            short4 b; b.x = (short)f2bf(v.x); b.y = (short)f2bf(v.y);
            b.z = (short)f2bf(v.z); b.w = (short)f2bf(v.w);
            *(short4*)&sA[row * 72 + ac4 * 4] = b;
        }
        __syncthreads();
        #pragma unroll
        for (int kk = 0; kk < 2; ++kk) {
            const int koff = kk * 32 + lq * 8;
            const int cb = kk * 4 + lq;
            const int scb = cb ^ (lm & 7);
            bf16x8 a[4], b[4];
            #pragma unroll
            for (int mt = 0; mt < 4; ++mt)
                a[mt] = *(const bf16x8*)&sA[(mt * 16 + lm) * 72 + koff];
            #pragma unroll
            for (int nt = 0; nt < 4; ++nt)
                b[nt] = *(const bf16x8*)&sBw[(nt * 16 + lm) * 64 + scb * 8];
            #pragma unroll
            for (int mt = 0; mt < 4; ++mt)
                #pragma unroll
                for (int nt = 0; nt < 4; ++nt)
                    acc[mt][nt] = __builtin_amdgcn_mfma_f32_16x16x32_bf16(
                        a[mt], b[nt], acc[mt][nt], 0, 0, 0);
        }
        __syncthreads();
    }
    #pragma unroll
    for (int mt = 0; mt < 4; ++mt)
        #pragma unroll
        for (int nt = 0; nt < 4; ++nt) {
            int col = w * 64 + nt * 16 + lm;
            #pragma unroll
            for (int r = 0; r < 4; ++r) {
                int rl = mt * 16 + lq * 4 + r;
                atomicAdd(out + (size_t)(m0 + rl) * DOUT + col,
                          acc[mt][nt][r] * disS[rl]);
            }
        }
}

// ---------------- kernel 4: reduce 4 split-K partials ----------------
__global__ __launch_bounds__(256) void k_reduce(const float4* __restrict__ p,
                                                float4* __restrict__ out) {
    const size_t i = (size_t)blockIdx.x * 256 + threadIdx.x;
    const size_t stride = (size_t)NROWS * DOUT / 4;
    float4 a = p[i], b = p[i + stride], c = p[i + 2 * stride], d = p[i + 3 * stride];
    float4 r;
    r.x = (a.x + b.x) + (c.x + d.x);
    r.y = (a.y + b.y) + (c.y + d.y);
    r.z = (a.z + b.z) + (c.z + d.z);
    r.w = (a.w + b.w) + (c.w + d.w);
    out[i] = r;
}

// ---------------- fallback rowsum (no Abf write) ----------------
__global__ __launch_bounds__(256) void k_rowsum(const float* __restrict__ A,
                                                float* __restrict__ dis) {
    const int wave = threadIdx.x >> 6, lane = threadIdx.x & 63;
    const int row = (blockIdx.x << 2) + wave;
    const float4* rp = (const float4*)(A + (size_t)row * KDIM);
    float s0 = 0.f, s1 = 0.f;
    #pragma unroll
    for (int it = 0; it < 32; it += 2) {
        float4 v0 = rp[(it + 0) * 64 + lane];
        float4 v1 = rp[(it + 1) * 64 + lane];
        s0 += (v0.x + v0.y) + (v0.z + v0.w);
        s1 += (v1.x + v1.y) + (v1.z + v1.w);
    }
    float s = s0 + s1;
    #pragma unroll
    for (int off = 32; off > 0; off >>= 1) s += __shfl_down(s, off, 64);
    if (lane == 0) dis[row] = rsqrtf(s);
}

extern "C" void kernel_launch(void* const* d_in, const int* in_sizes, int n_in,
                              void* d_out, int out_size, void* d_ws, size_t ws_size,
                              hipStream_t stream) {
    const float* X = (const float*)d_in[0];           // [8192,256]
    const float* A = (const float*)d_in[1];           // [8192,8192]
    const float* W = (const float*)d_in[2];           // [256,256]
    float* out = (float*)d_out;
    char* ws = (char*)d_ws;
    float* dis = (float*)ws;                                        // 32 KB
    unsigned short* Zst = (unsigned short*)(ws + 32768);            // 4 MB  [256][8192] bf16
    unsigned short* Abf = (unsigned short*)(ws + 32768 + (4 << 20));        // 128 MB
    float* part = (float*)(ws + 32768 + (4 << 20) + (128ull << 20));        // 32 MB
    const size_t need_full = 32768 + (4ull << 20) + (128ull << 20) +
                             4ull * NROWS * DOUT * sizeof(float);
    const size_t need_min = 32768 + (4ull << 20);

    if (ws_size >= need_full) {
        k_rowsum_cvt<<<NROWS / 4, 256, 0, stream>>>(A, dis, Abf);
        k_xw<<<NROWS / 64, 256, 0, stream>>>(X, W, dis, Zst);
        k_gemm_bf<<<dim3(NROWS / 64, 4), 256, 0, stream>>>(Abf, Zst, dis, part);
        k_reduce<<<(NROWS * DOUT / 4) / 256, 256, 0, stream>>>((const float4*)part,
                                                               (float4*)out);
    } else if (ws_size >= need_min) {
        k_rowsum<<<NROWS / 4, 256, 0, stream>>>(A, dis);
        k_xw<<<NROWS / 64, 256, 0, stream>>>(X, W, dis, Zst);
        hipMemsetAsync(d_out, 0, (size_t)out_size * sizeof(float), stream);
        k_gemm_f32<<<dim3(NROWS / 64, 4), 256, 0, stream>>>(A, Zst, dis, out);
    }
}

// Round 3
// 457.565 us; speedup vs baseline: 1.0174x; 1.0174x over previous
//
#include <hip/hip_runtime.h>
#include <stdint.h>

#define NROWS 8192
#define KDIM  8192
#define DIN   256
#define DOUT  256

typedef __attribute__((ext_vector_type(8))) short bf16x8;   // 8 bf16 in 4 VGPRs
typedef __attribute__((ext_vector_type(4))) float f32x4;

__device__ __forceinline__ unsigned short f2bf(float f) {
    union { float f; unsigned u; } v; v.f = f;
    unsigned r = v.u + 0x7FFFu + ((v.u >> 16) & 1u);   // RNE
    return (unsigned short)(r >> 16);
}

__device__ __forceinline__ void async_load16(const void* g, void* l) {
    __builtin_amdgcn_global_load_lds(
        (__attribute__((address_space(1))) void*)(void*)g,
        (__attribute__((address_space(3))) void*)l, 16, 0, 0);
}

// ---------------- kernel 1: dis[i] = rsqrt(rowsum(A)) ----------------
// 256 MiB streaming read, BW-bound (~45 us).
__global__ __launch_bounds__(256) void k_rowsum(const float* __restrict__ A,
                                                float* __restrict__ dis) {
    const int wave = threadIdx.x >> 6, lane = threadIdx.x & 63;
    const int row = (blockIdx.x << 2) + wave;
    const float4* rp = (const float4*)(A + (size_t)row * KDIM);
    float s0 = 0.f, s1 = 0.f;
    #pragma unroll
    for (int it = 0; it < 32; it += 2) {
        float4 v0 = rp[(it + 0) * 64 + lane];
        float4 v1 = rp[(it + 1) * 64 + lane];
        s0 += (v0.x + v0.y) + (v0.z + v0.w);
        s1 += (v1.x + v1.y) + (v1.z + v1.w);
    }
    float s = s0 + s1;
    #pragma unroll
    for (int off = 32; off > 0; off >>= 1) s += __shfl_down(s, off, 64);
    if (lane == 0) dis[row] = rsqrtf(s);
}

// ---------------- kernel 2: Zst[n][j] = dis[j] * (X @ W^T)[j][n]  (bf16, transposed) ----------------
__global__ __launch_bounds__(256, 2) void k_xw(const float* __restrict__ X,
                                               const float* __restrict__ W,
                                               const float* __restrict__ dis,
                                               unsigned short* __restrict__ Zst) {
    __shared__ short sX[64 * 72];
    __shared__ short sW[256 * 72];
    __shared__ float disS[64];
    const int tid = threadIdx.x;
    const int w = tid >> 6, lane = tid & 63, lm = lane & 15, lq = lane >> 4;
    const int j0 = blockIdx.x * 64;
    if (tid < 64) disS[tid] = dis[j0 + tid];
    f32x4 acc[4][4] = {};

    for (int s = 0; s < 4; ++s) {
        const int k0 = s * 64;
        #pragma unroll
        for (int i = 0; i < 4; ++i) {
            int e = tid + i * 256;
            int row = e >> 4, c4 = e & 15;
            float4 v = *(const float4*)(X + (size_t)(j0 + row) * DIN + k0 + c4 * 4);
            short4 b; b.x = (short)f2bf(v.x); b.y = (short)f2bf(v.y);
            b.z = (short)f2bf(v.z); b.w = (short)f2bf(v.w);
            *(short4*)&sX[row * 72 + c4 * 4] = b;
        }
        #pragma unroll
        for (int i = 0; i < 16; ++i) {
            int e = tid + i * 256;
            int row = e >> 4, c4 = e & 15;
            float4 v = *(const float4*)(W + (size_t)row * DIN + k0 + c4 * 4);
            short4 b; b.x = (short)f2bf(v.x); b.y = (short)f2bf(v.y);
            b.z = (short)f2bf(v.z); b.w = (short)f2bf(v.w);
            *(short4*)&sW[row * 72 + c4 * 4] = b;
        }
        __syncthreads();
        #pragma unroll
        for (int kk = 0; kk < 2; ++kk) {
            const int koff = kk * 32 + lq * 8;
            bf16x8 a[4], b[4];
            #pragma unroll
            for (int mt = 0; mt < 4; ++mt)
                a[mt] = *(const bf16x8*)&sX[(mt * 16 + lm) * 72 + koff];
            #pragma unroll
            for (int nt = 0; nt < 4; ++nt)
                b[nt] = *(const bf16x8*)&sW[(w * 64 + nt * 16 + lm) * 72 + koff];
            #pragma unroll
            for (int mt = 0; mt < 4; ++mt)
                #pragma unroll
                for (int nt = 0; nt < 4; ++nt)
                    acc[mt][nt] = __builtin_amdgcn_mfma_f32_16x16x32_bf16(
                        a[mt], b[nt], acc[mt][nt], 0, 0, 0);
        }
        __syncthreads();
    }

    #pragma unroll
    for (int mt = 0; mt < 4; ++mt)
        #pragma unroll
        for (int nt = 0; nt < 4; ++nt)
            #pragma unroll
            for (int r = 0; r < 4; ++r) {
                int jl = mt * 16 + lq * 4 + r;
                int n  = w * 64 + nt * 16 + lm;
                float v = acc[mt][nt][r] * disS[jl];
                sW[n * 72 + jl] = (short)f2bf(v);
            }
    __syncthreads();
    #pragma unroll
    for (int it = 0; it < 8; ++it) {
        int e = tid + it * 256;
        int n = e >> 3, ch = e & 7;
        bf16x8 val = *(const bf16x8*)&sW[n * 72 + ch * 8];
        *(bf16x8*)(Zst + (size_t)n * NROWS + j0 + ch * 8) = val;
    }
}

// ---------------- kernel 3: out[i][o] += dis[i] * sum_j A[i][j] * Zst[o][j] ----------------
// A read fp32 directly (no intermediate), cvt in VALU; B via global_load_lds.
// BM=64, BN=256, BK=64, SPLITK=4 -> 512 blocks, 2/CU; atomic accumulate to out.
__global__ __launch_bounds__(256, 2) void k_gemm(const float* __restrict__ A,
                                                 const unsigned short* __restrict__ Zst,
                                                 const float* __restrict__ dis,
                                                 float* __restrict__ out) {
    __shared__ short sA[64 * 72];     // padded stride (144 B) -> 2-way banks (free)
    __shared__ short sB[256 * 64];    // 4 wave-slabs, packed, XOR-swizzled 16B chunks
    __shared__ float disS[64];
    const int tid = threadIdx.x;
    const int w = tid >> 6, lane = tid & 63, lm = lane & 15, lq = lane >> 4;
    const int m0 = blockIdx.x * 64;
    const int split = blockIdx.y;
    const int kbase = split * 2048;
    if (tid < 64) disS[tid] = dis[m0 + tid];
    f32x4 acc[4][4] = {};
    short* sBw = &sB[w * 4096];
    const int arow = tid >> 4, ac4 = tid & 15;
    const int swz = (lane & 7) ^ (lane >> 3);     // LDS slot sc holds chunk sc ^ (row&7)
    const unsigned short* gB =
        Zst + (size_t)(w * 64 + (lane >> 3)) * KDIM + kbase + swz * 8;

    for (int s = 0; s < 32; ++s) {
        const int k0 = kbase + s * 64;
        #pragma unroll
        for (int i = 0; i < 8; ++i)
            async_load16(gB + s * 64 + (size_t)i * 8 * KDIM, &sBw[i * 512]);
        #pragma unroll
        for (int i = 0; i < 4; ++i) {
            int row = arow + i * 16;
            float4 v = *(const float4*)(A + (size_t)(m0 + row) * KDIM + k0 + ac4 * 4);
            short4 b; b.x = (short)f2bf(v.x); b.y = (short)f2bf(v.y);
            b.z = (short)f2bf(v.z); b.w = (short)f2bf(v.w);
            *(short4*)&sA[row * 72 + ac4 * 4] = b;
        }
        __syncthreads();
        #pragma unroll
        for (int kk = 0; kk < 2; ++kk) {
            const int koff = kk * 32 + lq * 8;
            const int cb = kk * 4 + lq;
            const int scb = cb ^ (lm & 7);        // undo swizzle (row&7 == lm&7)
            bf16x8 a[4], b[4];
            #pragma unroll
            for (int mt = 0; mt < 4; ++mt)
                a[mt] = *(const bf16x8*)&sA[(mt * 16 + lm) * 72 + koff];
            #pragma unroll
            for (int nt = 0; nt < 4; ++nt)
                b[nt] = *(const bf16x8*)&sBw[(nt * 16 + lm) * 64 + scb * 8];
            #pragma unroll
            for (int mt = 0; mt < 4; ++mt)
                #pragma unroll
                for (int nt = 0; nt < 4; ++nt)
                    acc[mt][nt] = __builtin_amdgcn_mfma_f32_16x16x32_bf16(
                        a[mt], b[nt], acc[mt][nt], 0, 0, 0);
        }
        __syncthreads();
    }

    #pragma unroll
    for (int mt = 0; mt < 4; ++mt)
        #pragma unroll
        for (int nt = 0; nt < 4; ++nt) {
            int col = w * 64 + nt * 16 + lm;
            #pragma unroll
            for (int r = 0; r < 4; ++r) {
                int rl = mt * 16 + lq * 4 + r;
                atomicAdd(out + (size_t)(m0 + rl) * DOUT + col,
                          acc[mt][nt][r] * disS[rl]);
            }
        }
}

extern "C" void kernel_launch(void* const* d_in, const int* in_sizes, int n_in,
                              void* d_out, int out_size, void* d_ws, size_t ws_size,
                              hipStream_t stream) {
    const float* X = (const float*)d_in[0];           // [8192,256]
    const float* A = (const float*)d_in[1];           // [8192,8192]
    const float* W = (const float*)d_in[2];           // [256,256]
    float* out = (float*)d_out;
    char* ws = (char*)d_ws;
    float* dis = (float*)ws;                                    // 32 KB
    unsigned short* Zst = (unsigned short*)(ws + 32768);        // 4 MB [256][8192] bf16

    k_rowsum<<<NROWS / 4, 256, 0, stream>>>(A, dis);
    k_xw<<<NROWS / 64, 256, 0, stream>>>(X, W, dis, Zst);
    hipMemsetAsync(d_out, 0, (size_t)out_size * sizeof(float), stream);
    k_gemm<<<dim3(NROWS / 64, 4), 256, 0, stream>>>(A, Zst, dis, out);
}